// Round 7
// baseline (497.439 us; speedup 1.0000x reference)
//
#include <hip/hip_runtime.h>

typedef float v4f __attribute__((ext_vector_type(4)));

#define NB   32     // batch
#define NT   8      // timesteps
#define NC   128    // channels
#define NQ   256    // float4s per (H*W)=1024 plane
#define CRED 32     // C/red
#define PADI 32     // ints of padding per arrival counter (128 B line)

// Cross-block traffic via relaxed agent-scope atomics only (LLC-direct) -> no
// fences, no cache-maintenance storms. ZERO __syncthreads in the main kernel:
// each wave owns one (b,c) plane, so all reductions are wave-internal
// (lockstep) and the only cross-wave sync is a per-batch 128-wave arrival
// counter at the LLC. Plain launch: 1024 blocks @ launch_bounds(256,4) =
// exactly 4 blocks/CU on 256 CUs -> all waves co-resident, spin is safe.
__device__ int                g_arrive[NB * PADI];      // per-batch arrival counters
__device__ unsigned long long g_xsum[2 * NB * NC];      // double-buffered mean bits

__global__ __launch_bounds__(256)
void lif_init() {
    int i = threadIdx.x + blockIdx.x * blockDim.x;
    if (i < NB * PADI) g_arrive[i] = 0;
}

__global__ __launch_bounds__(256, 4)
void dynamic_lif(const float* __restrict__ x,
                 const float* __restrict__ w1,
                 const float* __restrict__ b1,
                 const float* __restrict__ w2,
                 const float* __restrict__ b2,
                 float* __restrict__ out)
{
    const int tid = threadIdx.x;
    const int ln  = tid & 63;            // lane
    const int wv  = tid >> 6;            // wave in block
    const int gw  = blockIdx.x * 4 + wv; // global wave 0..4095
    const int b   = gw >> 7;             // batch
    const int c   = gw & 127;            // channel

    __shared__ double s_mlp[4][NC];      // wave-private mean staging (no barriers)

    const v4f* __restrict__ x4 = (const v4f*)x;
    v4f* __restrict__ o4       = (v4f*)out;

    v4f mem[4];
    #pragma unroll
    for (int q = 0; q < 4; ++q) mem[q] = (v4f){0.f, 0.f, 0.f, 0.f};

    float tau = 0.5f;                    // TAU0

    // prologue: this wave's plane for t=0 (fully coalesced: lane ln + 64q)
    v4f xv[4];
    {
        const long base0 = ((long)(b * NT + 0) * NC + c) * NQ;
        #pragma unroll
        for (int q = 0; q < 4; ++q)
            xv[q] = __builtin_nontemporal_load(x4 + base0 + ln + 64 * q);
    }

    for (int t = 0; t < NT; ++t) {
        const long obase = ((long)(b * NT + t) * NC + c) * NQ;
        double ps = 0.0;
        #pragma unroll
        for (int q = 0; q < 4; ++q) {
            v4f m = mem[q];
            m.x = fmaf(m.x, tau, xv[q].x);
            m.y = fmaf(m.y, tau, xv[q].y);
            m.z = fmaf(m.z, tau, xv[q].z);
            m.w = fmaf(m.w, tau, xv[q].w);
            ps += ((double)m.x + (double)m.y) + ((double)m.z + (double)m.w);
            v4f sp;
            sp.x = (m.x > 1.0f) ? 1.0f : 0.0f;   // zif(mem-1): exact (Sterbenz)
            sp.y = (m.y > 1.0f) ? 1.0f : 0.0f;
            sp.z = (m.z > 1.0f) ? 1.0f : 0.0f;
            sp.w = (m.w > 1.0f) ? 1.0f : 0.0f;
            __builtin_nontemporal_store(sp, o4 + obase + ln + 64 * q);
            m.x = (m.x > 1.0f) ? 0.0f : m.x;     // (1-spike)*mem
            m.y = (m.y > 1.0f) ? 0.0f : m.y;
            m.z = (m.z > 1.0f) ? 0.0f : m.z;
            m.w = (m.w > 1.0f) ? 0.0f : m.w;
            mem[q] = m;
        }

        if (t == NT - 1) break;          // last step: no tau needed

        // ---- wave-internal plane reduction (lockstep, no barriers) ----
        #pragma unroll
        for (int off = 32; off > 0; off >>= 1) ps += __shfl_down(ps, off);

        // ---- publish mean (LLC atomic), order it, arrive ----
        if (ln == 0)
            __hip_atomic_store(&g_xsum[(t & 1) * (NB * NC) + b * NC + c],
                               __double_as_longlong(ps * (1.0 / 1024.0)),
                               __ATOMIC_RELAXED, __HIP_MEMORY_SCOPE_AGENT);
        __builtin_amdgcn_s_waitcnt(0);   // wave-level: xsum store committed
        if (ln == 0)
            __hip_atomic_fetch_add(&g_arrive[b * PADI], 1,
                                   __ATOMIC_RELAXED, __HIP_MEMORY_SCOPE_AGENT);

        // prefetch next x AFTER arrive so it overlaps the spin + MLP
        {
            const long basen = ((long)(b * NT + (t + 1)) * NC + c) * NQ;
            #pragma unroll
            for (int q = 0; q < 4; ++q)
                xv[q] = __builtin_nontemporal_load(x4 + basen + ln + 64 * q);
        }

        // ---- per-batch barrier: 128 wave-arrivals, uniform all-lane spin ----
        const int target = 128 * (t + 1);    // monotonic; init kernel zeroes
        while (__hip_atomic_load(&g_arrive[b * PADI],
                                 __ATOMIC_RELAXED, __HIP_MEMORY_SCOPE_AGENT) < target)
            __builtin_amdgcn_s_sleep(2);

        // ---- MLP (128->32->1), computed redundantly per wave ----
        // stage this batch's 128 means into wave-private LDS (in-wave, no sync)
        {
            const unsigned long long* __restrict__ xmb =
                g_xsum + (t & 1) * (NB * NC) + b * NC;
            unsigned long long u0 =
                __hip_atomic_load(&xmb[ln], __ATOMIC_RELAXED, __HIP_MEMORY_SCOPE_AGENT);
            unsigned long long u1 =
                __hip_atomic_load(&xmb[ln + 64], __ATOMIC_RELAXED, __HIP_MEMORY_SCOPE_AGENT);
            s_mlp[wv][ln]      = __longlong_as_double(u0);
            s_mlp[wv][ln + 64] = __longlong_as_double(u1);
        }
        // lane pair (h, half): half-dot of hidden unit h over 64 channels
        const int h = ln & 31, half = ln >> 5;
        const float*  __restrict__ w1r = w1 + h * NC + half * 64;
        const double* __restrict__ xr  = &s_mlp[wv][half * 64];
        double acc = 0.0;
        #pragma unroll
        for (int j = 0; j < 64; ++j) acc += xr[j] * (double)w1r[j];
        acc += __shfl_down(acc, 32);     // combine halves -> lanes 0..31
        double e = 0.0;
        if (ln < CRED) {
            double full = acc + (double)b1[ln];
            double emb  = full > 0.0 ? full : 0.0;   // relu
            e = emb * (double)w2[ln];
        }
        #pragma unroll
        for (int off = 16; off > 0; off >>= 1) e += __shfl_down(e, off);
        double z = e + (double)b2[0];
        float ntau = (float)(1.0 / (1.0 + exp(-z)));
        tau = __shfl(ntau, 0);           // broadcast lane 0's tau
    }
}

extern "C" void kernel_launch(void* const* d_in, const int* in_sizes, int n_in,
                              void* d_out, int out_size, void* d_ws, size_t ws_size,
                              hipStream_t stream) {
    const float* x  = (const float*)d_in[0];
    const float* w1 = (const float*)d_in[1];
    const float* b1 = (const float*)d_in[2];
    const float* w2 = (const float*)d_in[3];
    const float* b2 = (const float*)d_in[4];
    float* out      = (float*)d_out;

    hipLaunchKernelGGL(lif_init, dim3((NB * PADI + 255) / 256), dim3(256),
                       0, stream);
    hipLaunchKernelGGL(dynamic_lif, dim3(NB * NC / 4), dim3(256), 0, stream,
                       x, w1, b1, w2, b2, out);
}

// Round 8
// 388.476 us; speedup vs baseline: 1.2805x; 1.2805x over previous
//
#include <hip/hip_runtime.h>

typedef float v4f __attribute__((ext_vector_type(4)));

#define NB   32     // batch
#define NT   8      // timesteps
#define NC   128    // channels
#define NQ   256    // float4s per (H*W)=1024 plane
#define CRED 32     // C/red
#define PADI 32     // ints of padding per arrival counter (128 B line)

// R7 lesson: all-lane LLC spins and wave-independent streaming order amplify
// HBM traffic 3x. Keep R6's block-lockstep layout + single-poller barrier.
// R6 lesson: per-step vmcnt(0) drains of 16.8 MB spike stores at every
// __syncthreads are the dominant stall -> split tau-solve (K1, no big stores)
// from spike-write (K2, no sync at all).
__device__ int                g_arrive[NB * PADI];      // per-batch arrival counters
__device__ unsigned long long g_xsum[2 * NB * NC];      // double-buffered mean bits
__device__ float              g_tau[NB * NT];           // [b][t]; t>=1 written by K1

__global__ __launch_bounds__(256)
void lif_init() {
    int i = threadIdx.x + blockIdx.x * blockDim.x;
    if (i < NB * PADI) g_arrive[i] = 0;
}

// ---------------------------------------------------------------------------
// K1: tau solver. Exact R6 skeleton (1024 blocks, block = (b, 4-channel
// group), mem in registers, LDS reduce, tid==0 poller, per-block MLP) but
// WITHOUT spike stores: barrier drains are cheap. Runs t=0..6 producing
// g_tau[b][1..7].
// ---------------------------------------------------------------------------
__global__ __launch_bounds__(256, 4)
void lif_tau(const float* __restrict__ x,
             const float* __restrict__ w1,
             const float* __restrict__ b1,
             const float* __restrict__ w2,
             const float* __restrict__ b2)
{
    const int bid = blockIdx.x;          // 0..1023
    const int b   = bid >> 5;            // batch
    const int c0  = (bid & 31) << 2;     // first of 4 channels
    const int tid = threadIdx.x;
    const int wv  = tid >> 6;
    const int ln  = tid & 63;

    __shared__ double s_part[4][4];
    __shared__ float  s_tau;

    const v4f* __restrict__ x4 = (const v4f*)x;

    v4f mem[4];
    #pragma unroll
    for (int p = 0; p < 4; ++p) mem[p] = (v4f){0.f, 0.f, 0.f, 0.f};

    float tau = 0.5f;                    // TAU0

    v4f xv[4];
    #pragma unroll
    for (int p = 0; p < 4; ++p)
        xv[p] = x4[((b * NT + 0) * NC + c0 + p) * NQ + tid];  // caching: warm L3 for K2

    for (int t = 0; t < NT - 1; ++t) {   // t = 0..6
        double psum[4];
        #pragma unroll
        for (int p = 0; p < 4; ++p) {
            v4f m = mem[p];
            m.x = fmaf(m.x, tau, xv[p].x);
            m.y = fmaf(m.y, tau, xv[p].y);
            m.z = fmaf(m.z, tau, xv[p].z);
            m.w = fmaf(m.w, tau, xv[p].w);
            psum[p] = ((double)m.x + (double)m.y) + ((double)m.z + (double)m.w);
            m.x = (m.x > 1.0f) ? 0.0f : m.x;     // reset; spike written by K2
            m.y = (m.y > 1.0f) ? 0.0f : m.y;
            m.z = (m.z > 1.0f) ? 0.0f : m.z;
            m.w = (m.w > 1.0f) ? 0.0f : m.w;
            mem[p] = m;
        }

        // prefetch next x so the loads fly across the reduce + barrier
        if (t + 1 < NT - 1) {
            #pragma unroll
            for (int p = 0; p < 4; ++p)
                xv[p] = x4[((b * NT + (t + 1)) * NC + c0 + p) * NQ + tid];
        }

        #pragma unroll
        for (int p = 0; p < 4; ++p) {
            double s = psum[p];
            #pragma unroll
            for (int off = 32; off > 0; off >>= 1) s += __shfl_down(s, off);
            if (ln == 0) s_part[p][wv] = s;
        }
        __syncthreads();
        if (tid < 4) {
            double s = (s_part[tid][0] + s_part[tid][1]) +
                       (s_part[tid][2] + s_part[tid][3]);
            __hip_atomic_store(&g_xsum[(t & 1) * (NB * NC) + b * NC + c0 + tid],
                               __double_as_longlong(s * (1.0 / 1024.0)),
                               __ATOMIC_RELAXED, __HIP_MEMORY_SCOPE_AGENT);
        }
        __syncthreads();   // publish stores committed (cheap: no big stores here)

        // ---- per-batch barrier: single tid==0 poller (R6-style) ----
        if (tid == 0) {
            __hip_atomic_fetch_add(&g_arrive[b * PADI], 1,
                                   __ATOMIC_RELAXED, __HIP_MEMORY_SCOPE_AGENT);
            const int target = 32 * (t + 1);     // monotonic; zeroed by lif_init
            while (__hip_atomic_load(&g_arrive[b * PADI],
                                     __ATOMIC_RELAXED, __HIP_MEMORY_SCOPE_AGENT) < target)
                __builtin_amdgcn_s_sleep(2);
        }
        __syncthreads();

        // tiny MLP (128->32->1), per block for its own batch
        double e = 0.0;
        if (tid < CRED) {
            const unsigned long long* __restrict__ xm =
                g_xsum + (t & 1) * (NB * NC) + b * NC;
            const float* __restrict__ w1r = w1 + tid * NC;
            double acc = (double)b1[tid];
            #pragma unroll 8
            for (int cc = 0; cc < NC; ++cc) {
                unsigned long long mb =
                    __hip_atomic_load(&xm[cc], __ATOMIC_RELAXED,
                                      __HIP_MEMORY_SCOPE_AGENT);
                acc += __longlong_as_double(mb) * (double)w1r[cc];
            }
            double emb = acc > 0.0 ? acc : 0.0;
            e = emb * (double)w2[tid];
        }
        #pragma unroll
        for (int off = 32; off > 0; off >>= 1) e += __shfl_down(e, off);
        if (tid == 0) {
            double z = e + (double)b2[0];
            float nt_tau = (float)(1.0 / (1.0 + exp(-z)));
            s_tau = nt_tau;
            if ((bid & 31) == 0)                 // one writer per batch
                g_tau[b * NT + t + 1] = nt_tau;  // plain store; kernel-end flush
        }
        __syncthreads();
        tau = s_tau;
    }
}

// ---------------------------------------------------------------------------
// K2: spike writer. Taus known -> ZERO synchronization. One block per (b,c)
// plane (4096 blocks); each thread recomputes its element's mem trajectory
// across all 8 steps with bit-identical arithmetic and streams spikes.
// ---------------------------------------------------------------------------
__global__ __launch_bounds__(256)
void lif_spike(const float* __restrict__ x, float* __restrict__ out)
{
    const int bid = blockIdx.x;          // 0..4095
    const int b   = bid >> 7;            // batch
    const int c   = bid & 127;           // channel
    const int tid = threadIdx.x;         // float4 index within plane

    const v4f* __restrict__ x4 = (const v4f*)x;
    v4f* __restrict__ o4       = (v4f*)out;

    float taus[NT];
    taus[0] = 0.5f;
    #pragma unroll
    for (int t = 1; t < NT; ++t) taus[t] = g_tau[b * NT + t];

    v4f m = (v4f){0.f, 0.f, 0.f, 0.f};
    #pragma unroll
    for (int t = 0; t < NT; ++t) {
        const long idx = ((long)(b * NT + t) * NC + c) * NQ + tid;
        v4f xv = x4[idx];                // L3-warm from K1
        m.x = fmaf(m.x, taus[t], xv.x);
        m.y = fmaf(m.y, taus[t], xv.y);
        m.z = fmaf(m.z, taus[t], xv.z);
        m.w = fmaf(m.w, taus[t], xv.w);
        v4f sp;
        sp.x = (m.x > 1.0f) ? 1.0f : 0.0f;   // zif(mem-1): exact (Sterbenz)
        sp.y = (m.y > 1.0f) ? 1.0f : 0.0f;
        sp.z = (m.z > 1.0f) ? 1.0f : 0.0f;
        sp.w = (m.w > 1.0f) ? 1.0f : 0.0f;
        __builtin_nontemporal_store(sp, o4 + idx);
        m.x = (m.x > 1.0f) ? 0.0f : m.x;     // (1-spike)*mem
        m.y = (m.y > 1.0f) ? 0.0f : m.y;
        m.z = (m.z > 1.0f) ? 0.0f : m.z;
        m.w = (m.w > 1.0f) ? 0.0f : m.w;
    }
}

extern "C" void kernel_launch(void* const* d_in, const int* in_sizes, int n_in,
                              void* d_out, int out_size, void* d_ws, size_t ws_size,
                              hipStream_t stream) {
    const float* x  = (const float*)d_in[0];
    const float* w1 = (const float*)d_in[1];
    const float* b1 = (const float*)d_in[2];
    const float* w2 = (const float*)d_in[3];
    const float* b2 = (const float*)d_in[4];
    float* out      = (float*)d_out;

    hipLaunchKernelGGL(lif_init, dim3((NB * PADI + 255) / 256), dim3(256),
                       0, stream);
    hipLaunchKernelGGL(lif_tau, dim3(NB * NC / 4), dim3(256), 0, stream,
                       x, w1, b1, w2, b2);
    hipLaunchKernelGGL(lif_spike, dim3(NB * NC), dim3(256), 0, stream,
                       x, out);
}

// Round 10
// 300.638 us; speedup vs baseline: 1.6546x; 1.2922x over previous
//
#include <hip/hip_runtime.h>

typedef float v4f __attribute__((ext_vector_type(4)));

#define NB   32     // batch
#define NT   8      // timesteps
#define NC   128    // channels
#define NQ   256    // float4s per (H*W)=1024 plane
#define CRED 32     // C/red
#define PADI 32     // ints of padding per arrival counter (128 B line)

// R9 lesson: cross-block consumer loads must be control-flow-ordered after
// the spin -> confine ALL g_xsum consumption to wave 0 (the spinning wave),
// plus a compiler memory barrier. Waves 1-3 only consume s_tau via LDS +
// __syncthreads (workgroup fence: always safe).
// R8 lesson: parallel coalesced LLC fetch, never sequential atomic loads.
// R7 lesson: park threads at barriers; single-lane poller; block-lockstep
// streaming. R6 lesson: keep 135 MB spike stores out of the synchronized
// kernel (K1/K2 split; K2 measured ~29 us).
__device__ int                g_arrive[NB * PADI];      // per-batch arrival counters
__device__ unsigned long long g_xsum[2 * NB * NC];      // double-buffered mean bits
__device__ float              g_tau[NB * NT];           // [b][t]; t>=1 written by K1

__global__ __launch_bounds__(256)
void lif_init() {
    int i = threadIdx.x + blockIdx.x * blockDim.x;
    if (i < NB * PADI) g_arrive[i] = 0;
}

// ---------------------------------------------------------------------------
// K1: tau solver. 1024 blocks (block = (b, 4-channel group)), mem in
// registers, no spike stores. Per step: fma/reduce -> wave-0 publishes means
// (LLC atomics) + arrives -> all waves prefetch next x (overlaps spin) ->
// wave-0 lane-0 spins, wave-0 fetches 128 means in parallel -> LDS -> wave-0
// MLP (128->32->1) -> s_tau -> one __syncthreads -> everyone reads tau.
// ---------------------------------------------------------------------------
__global__ __launch_bounds__(256, 4)
void lif_tau(const float* __restrict__ x,
             const float* __restrict__ w1,
             const float* __restrict__ b1,
             const float* __restrict__ w2,
             const float* __restrict__ b2)
{
    const int bid = blockIdx.x;          // 0..1023
    const int b   = bid >> 5;            // batch
    const int c0  = (bid & 31) << 2;     // first of 4 channels
    const int tid = threadIdx.x;
    const int wv  = tid >> 6;
    const int ln  = tid & 63;

    __shared__ double s_part[4][4];
    __shared__ double s_mlp[NC];         // staged means for this batch
    __shared__ float  s_tau;

    const v4f* __restrict__ x4 = (const v4f*)x;

    v4f mem[4];
    #pragma unroll
    for (int p = 0; p < 4; ++p) mem[p] = (v4f){0.f, 0.f, 0.f, 0.f};

    float tau = 0.5f;                    // TAU0

    v4f xv[4];
    #pragma unroll
    for (int p = 0; p < 4; ++p)
        xv[p] = x4[((b * NT + 0) * NC + c0 + p) * NQ + tid];  // caching: warms L3 for K2

    for (int t = 0; t < NT - 1; ++t) {   // t = 0..6, produces g_tau[b][1..7]
        double psum[4];
        #pragma unroll
        for (int p = 0; p < 4; ++p) {
            v4f m = mem[p];
            m.x = fmaf(m.x, tau, xv[p].x);
            m.y = fmaf(m.y, tau, xv[p].y);
            m.z = fmaf(m.z, tau, xv[p].z);
            m.w = fmaf(m.w, tau, xv[p].w);
            psum[p] = ((double)m.x + (double)m.y) + ((double)m.z + (double)m.w);
            m.x = (m.x > 1.0f) ? 0.0f : m.x;     // reset; spikes written by K2
            m.y = (m.y > 1.0f) ? 0.0f : m.y;
            m.z = (m.z > 1.0f) ? 0.0f : m.z;
            m.w = (m.w > 1.0f) ? 0.0f : m.w;
            mem[p] = m;
        }

        #pragma unroll
        for (int p = 0; p < 4; ++p) {
            double s = psum[p];
            #pragma unroll
            for (int off = 32; off > 0; off >>= 1) s += __shfl_down(s, off);
            if (ln == 0) s_part[p][wv] = s;
        }
        __syncthreads();                 // barrier A: s_part ready

        if (wv == 0) {
            if (ln < 4) {                // combine 4 waves, publish 4 means
                double s = (s_part[ln][0] + s_part[ln][1]) +
                           (s_part[ln][2] + s_part[ln][3]);
                __hip_atomic_store(&g_xsum[(t & 1) * (NB * NC) + b * NC + c0 + ln],
                                   __double_as_longlong(s * (1.0 / 1024.0)),
                                   __ATOMIC_RELAXED, __HIP_MEMORY_SCOPE_AGENT);
            }
            __builtin_amdgcn_s_waitcnt(0);   // publish committed at LLC (wave 0 only)
            if (ln == 0)
                __hip_atomic_fetch_add(&g_arrive[b * PADI], 1,
                                       __ATOMIC_RELAXED, __HIP_MEMORY_SCOPE_AGENT);
        }

        // all waves: prefetch next x now — overlaps wave 0's spin below
        if (t + 1 < NT - 1) {
            #pragma unroll
            for (int p = 0; p < 4; ++p)
                xv[p] = x4[((b * NT + (t + 1)) * NC + c0 + p) * NQ + tid];
        }

        if (wv == 0) {
            // lane-0 spin; whole wave rides the loop -> control-flow ordering
            if (ln == 0) {
                const int target = 32 * (t + 1);  // monotonic; zeroed by lif_init
                while (__hip_atomic_load(&g_arrive[b * PADI],
                                         __ATOMIC_RELAXED,
                                         __HIP_MEMORY_SCOPE_AGENT) < target)
                    __builtin_amdgcn_s_sleep(2);
            }
            asm volatile("" ::: "memory");   // no compiler hoist above the spin

            // parallel coalesced fetch: 64 lanes x 2 means -> LDS
            {
                const unsigned long long* __restrict__ xm =
                    g_xsum + (t & 1) * (NB * NC) + b * NC;
                unsigned long long u0 = __hip_atomic_load(
                    &xm[ln], __ATOMIC_RELAXED, __HIP_MEMORY_SCOPE_AGENT);
                unsigned long long u1 = __hip_atomic_load(
                    &xm[ln + 64], __ATOMIC_RELAXED, __HIP_MEMORY_SCOPE_AGENT);
                s_mlp[ln]      = __longlong_as_double(u0);
                s_mlp[ln + 64] = __longlong_as_double(u1);
            }

            // MLP (128->32->1) on wave 0, bit-identical summation order
            double e = 0.0;
            if (ln < CRED) {
                const float* __restrict__ w1r = w1 + ln * NC;
                double acc = (double)b1[ln];
                #pragma unroll 8
                for (int cc = 0; cc < NC; ++cc)
                    acc += s_mlp[cc] * (double)w1r[cc];
                double emb = acc > 0.0 ? acc : 0.0;
                e = emb * (double)w2[ln];
            }
            #pragma unroll
            for (int off = 32; off > 0; off >>= 1) e += __shfl_down(e, off);
            if (ln == 0) {
                double z = e + (double)b2[0];
                float nt_tau = (float)(1.0 / (1.0 + exp(-z)));
                s_tau = nt_tau;
                if ((bid & 31) == 0)                 // one writer per batch
                    g_tau[b * NT + t + 1] = nt_tau;  // flushed at kernel end
            }
        }
        __syncthreads();                 // barrier B: s_tau ready
        tau = s_tau;
    }
}

// ---------------------------------------------------------------------------
// K2: spike writer. Taus known -> ZERO synchronization. One block per (b,c)
// plane (4096 blocks); each thread recomputes its element's mem trajectory
// across all 8 steps with bit-identical arithmetic and streams spikes.
// Measured ~29 us (R8) — near the 135 MB write floor.
// ---------------------------------------------------------------------------
__global__ __launch_bounds__(256)
void lif_spike(const float* __restrict__ x, float* __restrict__ out)
{
    const int bid = blockIdx.x;          // 0..4095
    const int b   = bid >> 7;            // batch
    const int c   = bid & 127;           // channel
    const int tid = threadIdx.x;         // float4 index within plane

    const v4f* __restrict__ x4 = (const v4f*)x;
    v4f* __restrict__ o4       = (v4f*)out;

    float taus[NT];
    taus[0] = 0.5f;
    #pragma unroll
    for (int t = 1; t < NT; ++t) taus[t] = g_tau[b * NT + t];

    v4f m = (v4f){0.f, 0.f, 0.f, 0.f};
    #pragma unroll
    for (int t = 0; t < NT; ++t) {
        const long idx = ((long)(b * NT + t) * NC + c) * NQ + tid;
        v4f xv = x4[idx];                // L3-warm from K1
        m.x = fmaf(m.x, taus[t], xv.x);
        m.y = fmaf(m.y, taus[t], xv.y);
        m.z = fmaf(m.z, taus[t], xv.z);
        m.w = fmaf(m.w, taus[t], xv.w);
        v4f sp;
        sp.x = (m.x > 1.0f) ? 1.0f : 0.0f;   // zif(mem-1): exact (Sterbenz)
        sp.y = (m.y > 1.0f) ? 1.0f : 0.0f;
        sp.z = (m.z > 1.0f) ? 1.0f : 0.0f;
        sp.w = (m.w > 1.0f) ? 1.0f : 0.0f;
        __builtin_nontemporal_store(sp, o4 + idx);
        m.x = (m.x > 1.0f) ? 0.0f : m.x;     // (1-spike)*mem
        m.y = (m.y > 1.0f) ? 0.0f : m.y;
        m.z = (m.z > 1.0f) ? 0.0f : m.z;
        m.w = (m.w > 1.0f) ? 0.0f : m.w;
    }
}

extern "C" void kernel_launch(void* const* d_in, const int* in_sizes, int n_in,
                              void* d_out, int out_size, void* d_ws, size_t ws_size,
                              hipStream_t stream) {
    const float* x  = (const float*)d_in[0];
    const float* w1 = (const float*)d_in[1];
    const float* b1 = (const float*)d_in[2];
    const float* w2 = (const float*)d_in[3];
    const float* b2 = (const float*)d_in[4];
    float* out      = (float*)d_out;

    hipLaunchKernelGGL(lif_init, dim3((NB * PADI + 255) / 256), dim3(256),
                       0, stream);
    hipLaunchKernelGGL(lif_tau, dim3(NB * NC / 4), dim3(256), 0, stream,
                       x, w1, b1, w2, b2);
    hipLaunchKernelGGL(lif_spike, dim3(NB * NC), dim3(256), 0, stream,
                       x, out);
}